// Round 8
// baseline (112.188 us; speedup 1.0000x reference)
//
#include <hip/hip_runtime.h>

#define NPTS   65536
#define DIM    64
#define KCODES 1024
#define HW     4096
#define CH     64           // codes per LDS chunk (64 x 128 B = 8 KB)
#define NCH    16           // KCODES / CH

typedef __attribute__((ext_vector_type(8))) short  short8;
typedef __attribute__((ext_vector_type(4))) float  floatx4;

__device__ __forceinline__ short f2bf(float f) {   // RNE fp32 -> bf16
    unsigned u = __builtin_bit_cast(unsigned, f);
    u = (u + 0x7FFFu + ((u >> 16) & 1u)) >> 16;
    return (short)u;
}
__device__ __forceinline__ float bf2f(short s) {
    unsigned u = ((unsigned)(unsigned short)s) << 16;
    return __builtin_bit_cast(float, u);
}
// async 16 B global -> LDS (lds dest = wave-uniform base + lane*16)
__device__ __forceinline__ void gl_lds16(const void* g, void* l) {
    __builtin_amdgcn_global_load_lds(
        (const __attribute__((address_space(1))) unsigned int*)g,
        (__attribute__((address_space(3))) unsigned int*)l, 16, 0, 0);
}

// Prep: fp32 codebook -> bf16 codebook (d_ws) + (-0.5*||c_bf||^2).
__global__ void vq_prep(const float* __restrict__ cb, short* __restrict__ cbbf,
                        float* __restrict__ cbn) {
    int k = blockIdx.x * 256 + threadIdx.x;
    if (k >= KCODES) return;
    const float* row = cb + (size_t)k * DIM;
    float ns = 0.0f;
    #pragma unroll
    for (int c8 = 0; c8 < 8; ++c8) {
        short8 v;
        #pragma unroll
        for (int e = 0; e < 8; ++e) {
            short h = f2bf(row[c8 * 8 + e]);
            v[e] = h;
            float cf = bf2f(h);
            ns = fmaf(cf, cf, ns);
        }
        *(short8*)&cbbf[(size_t)k * DIM + c8 * 8] = v;
    }
    cbn[k] = -0.5f * ns;
}

// Main: 256 thr / 32 points per block, grid 2048 -> 8 blocks/CU = 8 waves/SIMD.
// Codebook streamed via async global_load_lds (zero VALU/VGPR staging) through
// 2 x 8 KB XOR-swizzled buffers: seg s of code row c lands at pos s^(c&7), so
// B-frag ds_read_b128 hits all 32 banks uniformly (no padding needed).
// Loss partials atomicAdd onto d_out's loss slot (poison 0xAA = -3e-13 fp32).
__global__ __launch_bounds__(256, 8) void vq_main(
    const float* __restrict__ x, const float* __restrict__ cb,
    const short* __restrict__ cbbf, const float* __restrict__ cbn,
    float* __restrict__ out, float* __restrict__ loss_ptr)
{
    __shared__ __align__(16) short s_cb[2][CH * DIM];   // 2 x 8 KB
    __shared__ float s_part[4][32];                      // per-wave best (packed)
    __shared__ float s_xn[32];                           // exact fp32 ||x||^2

    const int tid  = threadIdx.x;
    const int lane = tid & 63;
    const int wave = tid >> 6;     // 4 waves; wave w owns codes [w*16, w*16+16) of each chunk
    const int col  = lane & 15;    // MFMA m/n index
    const int quad = lane >> 4;    // MFMA k-group / C-row-group

    // ---- A fragments: all 4 waves load both 16-point m-tiles (L1/L2 absorb the 4x) ----
    const int pb = blockIdx.x * 32;
    short8 afrag[2][2];
    #pragma unroll
    for (int pt = 0; pt < 2; ++pt) {
        int n = pb + pt * 16 + col;
        const float* bp = x + ((size_t)(n >> 12) << 18) + (n & 4095);
        float ns = 0.0f;
        #pragma unroll
        for (int kh = 0; kh < 2; ++kh) {
            short8 f;
            #pragma unroll
            for (int j = 0; j < 8; ++j) {
                float v = bp[(size_t)(kh * 32 + quad * 8 + j) * HW];
                f[j] = f2bf(v);
                ns = fmaf(v, v, ns);
            }
            afrag[pt][kh] = f;
        }
        ns += __shfl_xor(ns, 16, 64);   // sum 4 quads -> full ||x||^2
        ns += __shfl_xor(ns, 32, 64);
        if (wave == 0 && quad == 0) s_xn[pt * 16 + col] = ns;
    }

    float best[2][4];
    #pragma unroll
    for (int pt = 0; pt < 2; ++pt)
        #pragma unroll
        for (int r = 0; r < 4; ++r) best[pt][r] = -3.4e38f;

    // staging lane geometry: instr i covers rows [(wave*2+i)*8, +8) of the chunk;
    // lane L -> row_local = L>>3, LDS seg pos = L&7, global seg = (L&7)^(L>>3).
    const int r_l = lane >> 3;
    const int sg  = (lane & 7) ^ r_l;

    // ---- stage chunk 0 ----
    #pragma unroll
    for (int i = 0; i < 2; ++i) {
        int row = (wave * 2 + i) * 8 + r_l;
        gl_lds16(cbbf + (size_t)row * DIM + sg * 8, &s_cb[0][(wave * 2 + i) * 512]);
    }
    __syncthreads();   // barrier drains vmcnt -> chunk 0 resident (also covers s_xn)

    // ---- chunk loop: async prefetch c+1 into other buffer, compute c, barrier ----
    for (int c = 0; c < NCH; ++c) {
        const int buf = c & 1;
        if (c + 1 < NCH) {
            #pragma unroll
            for (int i = 0; i < 2; ++i) {
                int row = (wave * 2 + i) * 8 + r_l;
                gl_lds16(cbbf + (size_t)((c + 1) * CH + row) * DIM + sg * 8,
                         &s_cb[buf ^ 1][(wave * 2 + i) * 512]);
            }
        }
        const int c_rel = wave * 16 + col;          // code within chunk
        const int g     = c * CH + c_rel;           // global code id
        const float initv = cbn[g];                 // L2-hot 64 B/tile
        const unsigned idxv = (unsigned)g;
        const short* base = &s_cb[buf][c_rel * DIM];
        short8 b0 = *(const short8*)(base + ((quad       ^ (col & 7)) * 8));  // seg quad
        short8 b1 = *(const short8*)(base + (((quad + 4) ^ (col & 7)) * 8));  // seg 4+quad
        floatx4 cinit = {initv, initv, initv, initv};
        #pragma unroll
        for (int pt = 0; pt < 2; ++pt) {
            floatx4 acc = __builtin_amdgcn_mfma_f32_16x16x32_bf16(afrag[pt][0], b0, cinit, 0, 0, 0);
            acc = __builtin_amdgcn_mfma_f32_16x16x32_bf16(afrag[pt][1], b1, acc, 0, 0, 0);
            #pragma unroll
            for (int r = 0; r < 4; ++r) {
                unsigned pbits = (__builtin_bit_cast(unsigned, acc[r]) & 0xFFFFFC00u) | idxv;
                best[pt][r] = fmaxf(best[pt][r], __builtin_bit_cast(float, pbits));
            }
        }
        __syncthreads();   // all waves done reading buf before it's re-staged (c+2)
    }

    // ---- reduce over 16 cols; publish per-wave best ----
    #pragma unroll
    for (int pt = 0; pt < 2; ++pt)
        #pragma unroll
        for (int r = 0; r < 4; ++r) {
            float v = best[pt][r];
            v = fmaxf(v, __shfl_xor(v, 1, 64));
            v = fmaxf(v, __shfl_xor(v, 2, 64));
            v = fmaxf(v, __shfl_xor(v, 4, 64));
            v = fmaxf(v, __shfl_xor(v, 8, 64));
            best[pt][r] = v;
        }
    if (col == 0) {
        #pragma unroll
        for (int pt = 0; pt < 2; ++pt)
            #pragma unroll
            for (int r = 0; r < 4; ++r)
                s_part[wave][pt * 16 + quad * 4 + r] = best[pt][r];
    }
    __syncthreads();

    // ---- epilogue: thread t -> point t&31, d-octet t>>5. Exact fp32 rows from cb. ----
    {
        int p  = tid & 31;
        int dg = tid >> 5;
        float m = fmaxf(fmaxf(s_part[0][p], s_part[1][p]),
                        fmaxf(s_part[2][p], s_part[3][p]));
        unsigned mu = __builtin_bit_cast(unsigned, m);
        int idx = (int)(mu & 1023u);
        int n = pb + p;
        float* op = out + ((size_t)(n >> 12) << 18) + (n & 4095);
        const float4* crow = (const float4*)(cb + (size_t)idx * DIM + dg * 8);
        float4 v0 = crow[0], v1 = crow[1];
        op[(size_t)(dg * 8 + 0) * HW] = v0.x;
        op[(size_t)(dg * 8 + 1) * HW] = v0.y;
        op[(size_t)(dg * 8 + 2) * HW] = v0.z;
        op[(size_t)(dg * 8 + 3) * HW] = v0.w;
        op[(size_t)(dg * 8 + 4) * HW] = v1.x;
        op[(size_t)(dg * 8 + 5) * HW] = v1.y;
        op[(size_t)(dg * 8 + 6) * HW] = v1.z;
        op[(size_t)(dg * 8 + 7) * HW] = v1.w;
        if (dg == 0) {   // lanes 0..31 of wave 0: one loss term per point
            float vtr = __builtin_bit_cast(float, mu & 0xFFFFFC00u);
            float lp = s_xn[p] - 2.0f * vtr;        // = ||x - c_best||^2
            lp += __shfl_down(lp, 16, 64);
            lp += __shfl_down(lp, 8, 64);
            lp += __shfl_down(lp, 4, 64);
            lp += __shfl_down(lp, 2, 64);
            lp += __shfl_down(lp, 1, 64);
            if (lane == 0)
                atomicAdd(loss_ptr, lp * (1.25f / ((float)NPTS * DIM)));
        }
    }
}

extern "C" void kernel_launch(void* const* d_in, const int* in_sizes, int n_in,
                              void* d_out, int out_size, void* d_ws, size_t ws_size,
                              hipStream_t stream) {
    const float* x  = (const float*)d_in[0];   // [16,64,64,64] NCHW fp32
    const float* cb = (const float*)d_in[1];   // [1024,64] fp32
    float* out      = (float*)d_out;           // quantized (4194304) + loss (1)
    float* loss_ptr = out + (size_t)NPTS * DIM;

    short* cbbf = (short*)d_ws;                                           // 128 KB
    float* cbn  = (float*)((char*)d_ws + KCODES * DIM * sizeof(short));   // 4 KB

    vq_prep<<<KCODES / 256, 256, 0, stream>>>(cb, cbbf, cbn);
    vq_main<<<NPTS / 32, 256, 0, stream>>>(x, cb, cbbf, cbn, out, loss_ptr);
}

// Round 9
// 95.377 us; speedup vs baseline: 1.1763x; 1.1763x over previous
//
#include <hip/hip_runtime.h>

#define NPTS   65536
#define DIM    64
#define KCODES 1024
#define HW     4096
#define CH     128          // codes per LDS chunk
#define NCH    8            // KCODES / CH
#define ROWP   72           // padded LDS row stride (bf16 elems): 144 B, 16B-aligned

typedef __attribute__((ext_vector_type(8))) short  short8;
typedef __attribute__((ext_vector_type(4))) float  floatx4;

__device__ __forceinline__ short f2bf(float f) {   // RNE fp32 -> bf16
    unsigned u = __builtin_bit_cast(unsigned, f);
    u = (u + 0x7FFFu + ((u >> 16) & 1u)) >> 16;
    return (short)u;
}

// ---------------- Phase 1: argmin scores + loss partials (no strided IO) ----
// R6's proven body; outputs: ps[n] = packed (score|idx) per point (coalesced),
// partials[block] = per-block sum of ||x - c_best||^2. No atomics.
__global__ __launch_bounds__(512, 4) void vq_score(
    const float* __restrict__ x, const float* __restrict__ cb,
    float* __restrict__ ps, float* __restrict__ partials)
{
    __shared__ __align__(16) short s_cb[CH * ROWP];   // 18 KB chunk
    __shared__ float s_cbn[CH];
    __shared__ float s_part[2][128];
    __shared__ float s_xn[128];
    __shared__ float s_red[2];

    const int tid  = threadIdx.x;
    const int lane = tid & 63;
    const int wave = tid >> 6;     // 8 waves
    const int col  = lane & 15;
    const int quad = lane >> 4;
    const int pg   = wave & 3;     // point group: 32 points
    const int kc   = wave >> 2;    // code half within chunk: 64 codes

    // A fragments (2 point-tiles) + exact fp32 ||x||^2
    const int pb = blockIdx.x * 128 + pg * 32;
    short8 afrag[2][2];
    #pragma unroll
    for (int pt = 0; pt < 2; ++pt) {
        int n = pb + pt * 16 + col;
        const float* bp = x + ((size_t)(n >> 12) << 18) + (n & 4095);
        float ns = 0.0f;
        #pragma unroll
        for (int kh = 0; kh < 2; ++kh) {
            short8 f;
            #pragma unroll
            for (int j = 0; j < 8; ++j) {
                float v = bp[(size_t)(kh * 32 + quad * 8 + j) * HW];
                f[j] = f2bf(v);
                ns = fmaf(v, v, ns);
            }
            afrag[pt][kh] = f;
        }
        ns += __shfl_xor(ns, 16, 64);
        ns += __shfl_xor(ns, 32, 64);
        if (kc == 0 && quad == 0) s_xn[pg * 32 + pt * 16 + col] = ns;
    }

    float best[2][4];
    #pragma unroll
    for (int pt = 0; pt < 2; ++pt)
        #pragma unroll
        for (int r = 0; r < 4; ++r) best[pt][r] = -3.4e38f;

    // chunk loop: stage+convert 128 codes (fused norms), one compute pass
    for (int c = 0; c < NCH; ++c) {
        __syncthreads();
        #pragma unroll
        for (int i = 0; i < 2; ++i) {
            int g = tid + 512 * i;
            const floatx4* p4 = (const floatx4*)cb + (size_t)c * 2048 + 2 * g;
            floatx4 va = p4[0], vb = p4[1];
            short8 v;
            v[0] = f2bf(va[0]); v[1] = f2bf(va[1]); v[2] = f2bf(va[2]); v[3] = f2bf(va[3]);
            v[4] = f2bf(vb[0]); v[5] = f2bf(vb[1]); v[6] = f2bf(vb[2]); v[7] = f2bf(vb[3]);
            int cc = g >> 3, part = g & 7;
            *(short8*)&s_cb[cc * ROWP + part * 8] = v;
            float ns = fmaf(va[0], va[0], fmaf(va[1], va[1], fmaf(va[2], va[2], va[3] * va[3])));
            ns = fmaf(vb[0], vb[0], fmaf(vb[1], vb[1], fmaf(vb[2], vb[2], fmaf(vb[3], vb[3], ns))));
            ns += __shfl_xor(ns, 1, 64);
            ns += __shfl_xor(ns, 2, 64);
            ns += __shfl_xor(ns, 4, 64);
            if ((tid & 7) == 0) s_cbn[cc] = -0.5f * ns;
        }
        __syncthreads();
        #pragma unroll
        for (int ct = 0; ct < 4; ++ct) {
            int cc = kc * 64 + ct * 16 + col;
            float initv = s_cbn[cc];
            unsigned idxv = (unsigned)(c * CH + cc);
            const short* rp = &s_cb[cc * ROWP + quad * 8];
            short8 b0 = *(const short8*)rp;
            short8 b1 = *(const short8*)(rp + 32);
            floatx4 cinit = {initv, initv, initv, initv};
            #pragma unroll
            for (int pt = 0; pt < 2; ++pt) {
                floatx4 acc = __builtin_amdgcn_mfma_f32_16x16x32_bf16(afrag[pt][0], b0, cinit, 0, 0, 0);
                acc = __builtin_amdgcn_mfma_f32_16x16x32_bf16(afrag[pt][1], b1, acc, 0, 0, 0);
                #pragma unroll
                for (int r = 0; r < 4; ++r) {
                    unsigned pbits = (__builtin_bit_cast(unsigned, acc[r]) & 0xFFFFFC00u) | idxv;
                    best[pt][r] = fmaxf(best[pt][r], __builtin_bit_cast(float, pbits));
                }
            }
        }
    }

    // reduce over 16 cols; publish per-kc best
    #pragma unroll
    for (int pt = 0; pt < 2; ++pt)
        #pragma unroll
        for (int r = 0; r < 4; ++r) {
            float v = best[pt][r];
            v = fmaxf(v, __shfl_xor(v, 1, 64));
            v = fmaxf(v, __shfl_xor(v, 2, 64));
            v = fmaxf(v, __shfl_xor(v, 4, 64));
            v = fmaxf(v, __shfl_xor(v, 8, 64));
            best[pt][r] = v;
        }
    if (col == 0) {
        #pragma unroll
        for (int pt = 0; pt < 2; ++pt)
            #pragma unroll
            for (int r = 0; r < 4; ++r)
                s_part[kc][pg * 32 + pt * 16 + quad * 4 + r] = best[pt][r];
    }
    __syncthreads();

    // final: threads 0..127 own one point each; coalesced ps write + partial
    if (tid < 128) {
        float m = fmaxf(s_part[0][tid], s_part[1][tid]);
        ps[blockIdx.x * 128 + tid] = m;                       // 512 B coalesced
        unsigned mu = __builtin_bit_cast(unsigned, m);
        float vtr = __builtin_bit_cast(float, mu & 0xFFFFFC00u);
        float lp = s_xn[tid] - 2.0f * vtr;                    // ||x - c_best||^2
        #pragma unroll
        for (int off = 32; off > 0; off >>= 1)
            lp += __shfl_down(lp, off, 64);
        if (lane == 0) s_red[wave] = lp;                      // waves 0,1
    }
    __syncthreads();
    if (tid == 0) partials[blockIdx.x] = s_red[0] + s_red[1];
}

// ---------------- Phase 2: streaming emit ----------------------------------
// One block per (b,d) plane: b = B>>6, d = B&63. Stages cb[:,d] (4 KB) in LDS,
// reads the plane's packed scores vectorized, writes out[B*4096 .. +4096) as
// perfectly sequential stores. Block 0 additionally reduces the 512 loss
// partials and stores the final loss (plain store over poison; no atomic).
__global__ __launch_bounds__(256) void vq_emit(
    const float* __restrict__ cb, const float* __restrict__ ps,
    const float* __restrict__ partials, float* __restrict__ out,
    float* __restrict__ loss_ptr)
{
    __shared__ float s_col[KCODES];   // 4 KB codebook column
    __shared__ float s_lred[4];

    const int tid = threadIdx.x;
    const int B   = blockIdx.x;       // plane id
    const int d   = B & 63;
    const int b   = B >> 6;

    #pragma unroll
    for (int i = 0; i < 4; ++i)       // column gather (L2-hot 256 KB codebook)
        s_col[tid + 256 * i] = cb[(size_t)(tid + 256 * i) * DIM + d];
    __syncthreads();

    const floatx4* psp = (const floatx4*)(ps + (size_t)b * HW) + tid * 4;
    floatx4* op = (floatx4*)(out + (size_t)B * HW) + tid * 4;
    #pragma unroll
    for (int i = 0; i < 4; ++i) {     // 16 floats/thread, contiguous
        floatx4 pv = psp[i];
        floatx4 ov;
        #pragma unroll
        for (int e = 0; e < 4; ++e) {
            unsigned idx = __builtin_bit_cast(unsigned, pv[e]) & 1023u;
            ov[e] = s_col[idx];
        }
        op[i] = ov;                   // streaming, fully coalesced
    }

    if (B == 0) {                     // loss reduce: 512 partials -> scalar
        float s = partials[tid] + partials[tid + 256];
        #pragma unroll
        for (int off = 32; off > 0; off >>= 1)
            s += __shfl_down(s, off, 64);
        if ((tid & 63) == 0) s_lred[tid >> 6] = s;
        __syncthreads();
        if (tid == 0)
            *loss_ptr = (s_lred[0] + s_lred[1] + s_lred[2] + s_lred[3])
                        * (1.25f / ((float)NPTS * DIM));
    }
}

extern "C" void kernel_launch(void* const* d_in, const int* in_sizes, int n_in,
                              void* d_out, int out_size, void* d_ws, size_t ws_size,
                              hipStream_t stream) {
    const float* x  = (const float*)d_in[0];   // [16,64,64,64] NCHW fp32
    const float* cb = (const float*)d_in[1];   // [1024,64] fp32
    float* out      = (float*)d_out;           // quantized (4194304) + loss (1)
    float* loss_ptr = out + (size_t)NPTS * DIM;

    float* ps       = (float*)d_ws;                 // 256 KB packed scores
    float* partials = ps + NPTS;                    // 2 KB per-block partials

    vq_score<<<NPTS / 128, 512, 0, stream>>>(x, cb, ps, partials);
    vq_emit<<<(NPTS * DIM) / (256 * 16), 256, 0, stream>>>(cb, ps, partials, out, loss_ptr);
}